// Round 4
// baseline (252.820 us; speedup 1.0000x reference)
//
#include <hip/hip_runtime.h>
#include <hip/hip_bf16.h>
#include <stdint.h>

#define B_ 2
#define C_ 256
#define H_ 96
#define W_ 96
#define HW_ (H_*W_)

typedef _Float16 h2 __attribute__((ext_vector_type(2)));
typedef _Float16 h8 __attribute__((ext_vector_type(8)));

union H8U { h8 v; h2 h[4]; };

__device__ __forceinline__ float dot2f(h2 a, h2 b, float c) {
#if __has_builtin(__builtin_amdgcn_fdot2)
  return __builtin_amdgcn_fdot2(a, b, c, false);
#else
  return c + (float)a[0] * (float)b[0] + (float)a[1] * (float)b[1];
#endif
}

// ---------- (B, C, HW) f32  ->  (B, HW, C) f16 tile transpose (+scale) ----------
__global__ __launch_bounds__(256) void k_transpose(const float* __restrict__ in,
                                                   _Float16* __restrict__ out,
                                                   float scale) {
  __shared__ float t[32][33];
  const int b = blockIdx.z;
  const int p0 = blockIdx.x * 32, c0 = blockIdx.y * 32;
  const int tx = threadIdx.x, ty = threadIdx.y;
  const float* src = in + ((size_t)b * C_ + c0) * HW_ + p0;
#pragma unroll
  for (int i = 0; i < 4; ++i)
    t[ty + 8 * i][tx] = src[(size_t)(ty + 8 * i) * HW_ + tx];
  __syncthreads();
  _Float16* dst = out + ((size_t)b * HW_ + p0) * C_ + c0;
#pragma unroll
  for (int i = 0; i < 4; ++i)
    dst[(size_t)(ty + 8 * i) * C_ + tx] = (_Float16)(t[tx][ty + 8 * i] * scale);
}

// ---------- 2x2 avg pool on (B, h, w, C) f16 ----------
__global__ __launch_bounds__(256) void k_pool(const _Float16* __restrict__ in,
                                              _Float16* __restrict__ out,
                                              int hin, int win) {
  const int wout = win >> 1, hout = hin >> 1;
  int idx = blockIdx.x;
  const int X = idx % wout; idx /= wout;
  const int Y = idx % hout; const int b = idx / hout;
  const int c = threadIdx.x;
  const _Float16* p = in + (((size_t)b * hin + 2 * Y) * win + 2 * X) * C_ + c;
  const size_t rs = (size_t)win * C_;
  float v = (float)p[0] + (float)p[C_] + (float)p[rs] + (float)p[rs + C_];
  out[(((size_t)b * hout + Y) * wout + X) * C_ + c] = (_Float16)(v * 0.25f);
}

// workspace byte layout: [zero page 8KB][f1t][L0][L1][L2][L3]
#define F1OFF 8192u
#define L0OFF 9445376u
#define L1OFF 18882560u
#define L2OFF 21241856u
#define L3OFF 21831680u

#define DOT4(r, u)                                                  \
  do {                                                              \
    r = dot2f(u.h[0], f1h[0], r); r = dot2f(u.h[1], f1h[1], r);     \
    r = dot2f(u.h[2], f1h[2], r); r = dot2f(u.h[3], f1h[3], r);     \
  } while (0)

#define RED32(a)                \
  do {                          \
    a += __shfl_xor(a, 1);      \
    a += __shfl_xor(a, 2);      \
    a += __shfl_xor(a, 4);      \
    a += __shfl_xor(a, 8);      \
    a += __shfl_xor(a, 16);     \
  } while (0)

// ---------- main: per-pixel window rows streamed contiguously ----------
__global__ __launch_bounds__(256, 4) void k_corr(const char* __restrict__ ws,
                                                 const float* __restrict__ cent,
                                                 float* __restrict__ out) {
  __shared__ float dl[4][112];
  const int wid  = threadIdx.x >> 6;
  const int lane = threadIdx.x & 63;
  const int ch   = lane & 31;          // channel chunk (8 f16 = 16B)
  const int half = lane >> 5;          // even/odd position within 1KB load

  // XCD swizzle: blockIdx % 8 -> XCD. Each XCD gets a CONTIGUOUS yx range
  // (coalesced output lines stay within one L2); XCDs 0-3 batch 0, 4-7 batch 1.
  const int g    = blockIdx.x;
  const int xcd  = g & 7;
  const int slot = g >> 3;             // 0..575
  const int b    = xcd >> 2;
  const int ib   = (xcd & 3) * 576 + slot;   // block within batch
  const int yx   = ib * 4 + wid;
  const int pix  = b * HW_ + yx;

  const float cx = cent[(size_t)(b * 2 + 0) * HW_ + yx];
  const float cy = cent[(size_t)(b * 2 + 1) * HW_ + yx];

  // f1 chunk for this lane (8 channels, pre-scaled by 1/16)
  h2 f1h[4];
  {
    H8U u;
    u.v = *(const h8*)(ws + F1OFF + (size_t)pix * 512 + ch * 16);
    f1h[0] = u.h[0]; f1h[1] = u.h[1]; f1h[2] = u.h[2]; f1h[3] = u.h[3];
  }

  constexpr uint32_t LB[4] = {L0OFF, L1OFF, L2OFF, L3OFF};
  constexpr uint32_t PB[4] = {4718592u, 1179648u, 294912u, 73728u};

#pragma unroll
  for (int lvl = 0; lvl < 4; ++lvl) {
    const int hl = H_ >> lvl, wl = W_ >> lvl;
    const float sc  = 1.0f / (float)(1 << lvl);
    const float cxl = cx * sc, cyl = cy * sc;
    const float fx = floorf(cxl), fy = floorf(cyl);
    const int X0 = (int)fx - 4, Y0 = (int)fy - 4;
    const float wx1 = cxl - fx, wy1 = cyl - fy;
    const float wx0 = 1.0f - wx1, wy0 = 1.0f - wy1;
    // clamp the 10-wide row window fully in-bounds; shift store index by s
    const int Xc = min(max(X0, 0), wl - 10);
    const int s  = X0 - Xc;                    // in [-4, 5]
    const uint32_t lbase = LB[lvl] + (uint32_t)b * PB[lvl];

    dl[wid][lane] = 0.0f;
    if (lane < 48) dl[wid][lane + 64] = 0.0f;

    // 10 window rows; each row = 5 contiguous 1KB wave-loads (2 positions each)
#pragma unroll 2
    for (int r = 0; r < 10; ++r) {
      const int y = Y0 + r;
      const bool yv = (y >= 0) & (y < hl);
      const uint32_t rowb = yv ? (lbase + ((uint32_t)(y * wl + Xc) << 9)) : 0u;
      const char* rp = ws + rowb + half * 512 + ch * 16;
      H8U u0, u1, u2, u3, u4;
      u0.v = *(const h8*)(rp);
      u1.v = *(const h8*)(rp + 1024);
      u2.v = *(const h8*)(rp + 2048);
      u3.v = *(const h8*)(rp + 3072);
      u4.v = *(const h8*)(rp + 4096);
      float a0 = 0.f, a1 = 0.f, a2 = 0.f, a3 = 0.f, a4 = 0.f;
      DOT4(a0, u0); DOT4(a1, u1); DOT4(a2, u2); DOT4(a3, u3); DOT4(a4, u4);
      RED32(a0); RED32(a1); RED32(a2); RED32(a3); RED32(a4);
      if (ch == 0) {
        const int i0 = 0 + half - s;
        const int i1 = 2 + half - s;
        const int i2 = 4 + half - s;
        const int i3 = 6 + half - s;
        const int i4 = 8 + half - s;
        float* d = &dl[wid][r * 10];
        if ((unsigned)i0 < 10u) d[i0] = a0;
        if ((unsigned)i1 < 10u) d[i1] = a1;
        if ((unsigned)i2 < 10u) d[i2] = a2;
        if ((unsigned)i3 < 10u) d[i3] = a3;
        if ((unsigned)i4 < 10u) d[i4] = a4;
      }
    }

    // separable bilinear combine + store (per-wave; lgkmcnt orders LDS RAW)
#pragma unroll
    for (int rr = 0; rr < 2; ++rr) {
      const int o = rr * 64 + lane;
      if (o < 81) {
        const int a = o / 9, bq = o - a * 9;   // a = x index, bq = y index
        const float* d = dl[wid];
        const float d00 = d[bq * 10 + a],      d10 = d[bq * 10 + a + 1];
        const float d01 = d[bq * 10 + a + 10], d11 = d[bq * 10 + a + 11];
        const float v = wy0 * (wx0 * d00 + wx1 * d10) + wy1 * (wx0 * d01 + wx1 * d11);
        out[(size_t)(b * 324 + lvl * 81 + o) * HW_ + yx] = v;
      }
    }
  }
}

extern "C" void kernel_launch(void* const* d_in, const int* in_sizes, int n_in,
                              void* d_out, int out_size, void* d_ws, size_t ws_size,
                              hipStream_t stream) {
  (void)in_sizes; (void)n_in; (void)out_size; (void)ws_size;
  const float* f1   = (const float*)d_in[0];
  const float* f2   = (const float*)d_in[1];
  const float* cent = (const float*)d_in[2];
  float* out = (float*)d_out;

  char* ws = (char*)d_ws;
  _Float16* f1t = (_Float16*)(ws + F1OFF);
  _Float16* L0  = (_Float16*)(ws + L0OFF);
  _Float16* L1  = (_Float16*)(ws + L1OFF);
  _Float16* L2  = (_Float16*)(ws + L2OFF);
  _Float16* L3  = (_Float16*)(ws + L3OFF);

  hipMemsetAsync(d_ws, 0, 8192, stream);  // zero page for OOB window rows

  dim3 tb(32, 8, 1);
  dim3 tg(HW_ / 32, C_ / 32, B_);
  hipLaunchKernelGGL(k_transpose, tg, tb, 0, stream, f1, f1t, 0.0625f);
  hipLaunchKernelGGL(k_transpose, tg, tb, 0, stream, f2, L0, 1.0f);
  hipLaunchKernelGGL(k_pool, dim3(B_ * 48 * 48), dim3(256), 0, stream, L0, L1, 96, 96);
  hipLaunchKernelGGL(k_pool, dim3(B_ * 24 * 24), dim3(256), 0, stream, L1, L2, 48, 48);
  hipLaunchKernelGGL(k_pool, dim3(B_ * 12 * 12), dim3(256), 0, stream, L2, L3, 24, 24);
  hipLaunchKernelGGL(k_corr, dim3(B_ * HW_ / 4), dim3(256), 0, stream, ws, cent, out);
}